// Round 1
// baseline (3241.816 us; speedup 1.0000x reference)
//
#include <hip/hip_runtime.h>

#define CN0 50000
#define CE0 200000
#define CN1 100000
#define CE1 400000

// ---------------- fill ----------------
__global__ void fill_k(float* __restrict__ p, float v, int n) {
    int i = blockIdx.x * 256 + threadIdx.x;
    if (i < n) p[i] = v;
}

// ---------------- GEMM: Y[N,M] = X[N,K] @ W[K,M] (+bias[M]) (+add[N,M]) ----------------
// 64x64 tile, BK=16, 256 threads, 4x4 register tile per thread. fp32.
__global__ __launch_bounds__(256) void gemm_k(
        const float* __restrict__ X, const float* __restrict__ W,
        const float* __restrict__ bias, const float* __restrict__ add,
        float* __restrict__ Y, int N, int K, int M) {
    __shared__ float Xs[16][68];   // [k][row], pad to 68 (272B stride, 16B-aligned)
    __shared__ float Ws[16][68];   // [k][col]
    const int bm = blockIdx.y * 64;
    const int bn = blockIdx.x * 64;
    const int tid = threadIdx.x;
    const int tx = tid & 15, ty = tid >> 4;
    float acc[4][4] = {};
    for (int k0 = 0; k0 < K; k0 += 16) {
        #pragma unroll
        for (int i = 0; i < 4; ++i) {          // 1024 elems: 64 rows x 16 k
            int idx = tid + i * 256;
            int r = idx >> 4, c = idx & 15;
            int gr = bm + r;
            Xs[c][r] = (gr < N) ? X[(long)gr * K + k0 + c] : 0.f;
        }
        #pragma unroll
        for (int i = 0; i < 4; ++i) {          // 1024 elems: 16 k x 64 cols
            int idx = tid + i * 256;
            int r = idx >> 6, c = idx & 63;
            Ws[r][c] = W[(long)(k0 + r) * M + bn + c];   // M%64==0, K%16==0 guaranteed
        }
        __syncthreads();
        #pragma unroll
        for (int k = 0; k < 16; ++k) {
            float xv[4], wv[4];
            #pragma unroll
            for (int i = 0; i < 4; ++i) xv[i] = Xs[k][ty * 4 + i];
            #pragma unroll
            for (int j = 0; j < 4; ++j) wv[j] = Ws[k][tx * 4 + j];
            #pragma unroll
            for (int i = 0; i < 4; ++i)
                #pragma unroll
                for (int j = 0; j < 4; ++j) acc[i][j] += xv[i] * wv[j];
        }
        __syncthreads();
    }
    #pragma unroll
    for (int i = 0; i < 4; ++i) {
        int gr = bm + ty * 4 + i;
        if (gr >= N) continue;
        #pragma unroll
        for (int j = 0; j < 4; ++j) {
            int gc = bn + tx * 4 + j;
            float v = acc[i][j];
            if (bias) v += bias[gc];
            if (add)  v += add[(long)gr * M + gc];
            Y[(long)gr * M + gc] = v;
        }
    }
}

// ---------------- edge kernel: f = lrelu(FNi[src]+FNj[dst]+FEb[e>>sh]); ef_out = sum_h f; logits = f . attn ----------------
// one wave (64 lanes) per edge, H=2 fixed
__global__ __launch_bounds__(256) void edge_k(
        const float* __restrict__ FNi, const float* __restrict__ FNj,
        const float* __restrict__ FEb, const float* __restrict__ attn,
        const int* __restrict__ src, const int* __restrict__ dst,
        int E, int out_e, int fe_shift,
        float* __restrict__ ef_out, float* __restrict__ logits) {
    int e = blockIdx.x * 4 + (threadIdx.x >> 6);
    int lane = threadIdx.x & 63;
    if (e >= E) return;
    int s = src[e], d = dst[e];
    long fi = (long)s * (2 * out_e);
    long fj = (long)d * (2 * out_e);
    long fe = (long)(e >> fe_shift) * (2 * out_e);
    float l0 = 0.f, l1 = 0.f;
    for (int c = lane; c < out_e; c += 64) {
        float f0 = FNi[fi + c] + FNj[fj + c] + FEb[fe + c];
        f0 = f0 > 0.f ? f0 : 0.01f * f0;
        float f1 = FNi[fi + out_e + c] + FNj[fj + out_e + c] + FEb[fe + out_e + c];
        f1 = f1 > 0.f ? f1 : 0.01f * f1;
        l0 += f0 * attn[c];
        l1 += f1 * attn[out_e + c];
        ef_out[(long)e * out_e + c] = f0 + f1;
    }
    #pragma unroll
    for (int off = 32; off > 0; off >>= 1) {
        l0 += __shfl_down(l0, off);
        l1 += __shfl_down(l1, off);
    }
    if (lane == 0) { logits[2 * e] = l0; logits[2 * e + 1] = l1; }
}

// ---------------- segment max via atomic int/uint trick ----------------
__device__ __forceinline__ void atomicMaxF(float* addr, float v) {
    if (v >= 0.f) atomicMax((int*)addr, __float_as_int(v));
    else          atomicMin((unsigned int*)addr, __float_as_uint(v));
}

__global__ void segmax_k(const float* __restrict__ logits, const int* __restrict__ dst,
                         int E, float* __restrict__ emax) {
    int i = blockIdx.x * 256 + threadIdx.x;
    if (i >= E) return;
    int d = dst[i];
    atomicMaxF(&emax[2 * d],     logits[2 * i]);
    atomicMaxF(&emax[2 * d + 1], logits[2 * i + 1]);
}

// ---------------- ee = exp(logit - emax[dst]); denom[dst] += ee ----------------
__global__ void eednm_k(const float* __restrict__ logits, const int* __restrict__ dst,
                        int E, const float* __restrict__ emax,
                        float* __restrict__ ee, float* __restrict__ denom) {
    int i = blockIdx.x * 256 + threadIdx.x;
    if (i >= E) return;
    int d = dst[i];
    float e0 = expf(logits[2 * i]     - emax[2 * d]);
    float e1 = expf(logits[2 * i + 1] - emax[2 * d + 1]);
    ee[2 * i] = e0; ee[2 * i + 1] = e1;
    atomicAdd(&denom[2 * d],     e0);
    atomicAdd(&denom[2 * d + 1], e1);
}

// ---------------- scatter: out[dst] += a0*Hn[src][0,:] + a1*Hn[src][1,:]  (out_n=128, Hn stride 256) ----------------
__global__ __launch_bounds__(256) void scatter_k(
        const float* __restrict__ Hn, const float* __restrict__ ee,
        const float* __restrict__ denom, const int* __restrict__ src,
        const int* __restrict__ dst, int E, float* __restrict__ out) {
    int e = blockIdx.x * 4 + (threadIdx.x >> 6);
    int lane = threadIdx.x & 63;
    if (e >= E) return;
    int s = src[e], d = dst[e];
    float a0 = ee[2 * e]     / denom[2 * d];
    float a1 = ee[2 * e + 1] / denom[2 * d + 1];
    const float* h = Hn + (long)s * 256;
    float* o = out + (long)d * 128;
    #pragma unroll
    for (int c = lane; c < 128; c += 64)
        atomicAdd(&o[c], a0 * h[c] + a1 * h[128 + c]);
}

extern "C" void kernel_launch(void* const* d_in, const int* in_sizes, int n_in,
                              void* d_out, int out_size, void* d_ws, size_t ws_size,
                              hipStream_t stream) {
    const float* node_feats   = (const float*)d_in[0];
    const float* edge_feats   = (const float*)d_in[1];
    const float* node_path_in = (const float*)d_in[2];
    const float* edge_path_in = (const float*)d_in[3];
    const float* lin1_W = (const float*)d_in[32];
    const float* lin1_b = (const float*)d_in[33];
    const int* src0 = (const int*)d_in[34];
    const int* dst0 = (const int*)d_in[35];
    const int* src1 = (const int*)d_in[36];
    const int* dst1 = (const int*)d_in[37];

    float* out  = (float*)d_out;
    float* seg0 = out;              // nf        [50000,128]  (also holds nf1 mid-flight)
    float* seg1 = out + 6400000;    // ef2       [200000,128] (also holds ef1 mid-flight)
    float* seg2 = out + 32000000;   // node_path [100000,128] (also holds np1 mid-flight)
    float* seg3 = out + 44800000;   // edge_path [400000,64]

    float* ws     = (float*)d_ws;
    float* FNi    = ws;                   // 12.8M floats
    float* FNj    = FNi + 12800000;       // 12.8M
    float* Hn     = FNj + 12800000;       // 25.6M
    float* FE     = Hn  + 25600000;       // 51.2M
    float* EF     = FE  + 51200000;       // 25.6M (edge_path intermediate from stage 2a)
    float* np2    = EF  + 25600000;       // 12.8M
    float* logits = np2 + 12800000;       // 0.8M
    float* ee     = logits + 800000;      // 0.8M
    float* emax   = ee + 800000;          // 0.2M
    float* denom  = emax + 200000;        // 0.2M
    // total ~141M floats = ~563 MB of ws

    auto gemm = [&](const float* X, const float* W, const float* b, const float* add,
                    float* Y, int N, int K, int M) {
        dim3 g(M / 64, (N + 63) / 64);
        gemm_k<<<g, 256, 0, stream>>>(X, W, b, add, Y, N, K, M);
    };
    auto fill = [&](float* p, float v, int n) {
        fill_k<<<(n + 255) / 256, 256, 0, stream>>>(p, v, n);
    };
    // One EGAT layer. base = index of <pre>_ni in d_in.
    auto egat = [&](const float* nfeats, int N, int in_n,
                    const float* efeats, int fij_rows, int in_e,
                    int out_e, int fe_shift, int base,
                    const int* src, const int* dst, int E,
                    float* ef_out, float* h_out) {
        const float* Wni   = (const float*)d_in[base + 0];
        const float* Wnj   = (const float*)d_in[base + 1];
        const float* Wfij  = (const float*)d_in[base + 2];
        const float* Wnode = (const float*)d_in[base + 3];
        const float* bnode = (const float*)d_in[base + 4];
        const float* attn  = (const float*)d_in[base + 5];
        const float* bias  = (const float*)d_in[base + 6];
        gemm(nfeats, Wni,   nullptr, nullptr, FNi, N, in_n, 2 * out_e);
        gemm(nfeats, Wnj,   nullptr, nullptr, FNj, N, in_n, 2 * out_e);
        gemm(nfeats, Wnode, bnode,   nullptr, Hn,  N, in_n, 256);
        gemm(efeats, Wfij,  bias,    nullptr, FE,  fij_rows, in_e, 2 * out_e);
        fill(emax, -3.0e38f, 2 * N);
        fill(denom, 0.f, 2 * N);
        edge_k<<<(E + 3) / 4, 256, 0, stream>>>(FNi, FNj, FE, attn, src, dst,
                                                E, out_e, fe_shift, ef_out, logits);
        segmax_k<<<(E + 255) / 256, 256, 0, stream>>>(logits, dst, E, emax);
        eednm_k<<<(E + 255) / 256, 256, 0, stream>>>(logits, dst, E, emax, ee, denom);
        fill(h_out, 0.f, N * 128);
        scatter_k<<<(E + 3) / 4, 256, 0, stream>>>(Hn, ee, denom, src, dst, E, h_out);
    };

    // ---- Stage 1: EGAT on atom graph ----  nf1 -> seg0, ef1 -> seg1
    egat(node_feats, CN0, 128, edge_feats, CE0, 128, 128, 0, 4, src0, dst0, CE0, seg1, seg0);

    // ---- Lift: x11 = ef1 viewed as [100000,256]; np1 = x11@lin1_W + lin1_b + node_path_in -> seg2
    gemm(seg1, lin1_W, lin1_b, node_path_in, seg2, CN1, 256, 128);

    // ---- Stage 2a: path graph ----  ef -> EF (ws), h -> np2 (ws)
    egat(seg2, CN1, 128, edge_path_in, CE1, 64, 64, 0, 11, src1, dst1, CE1, EF, np2);

    // ---- Stage 2b: path graph ----  ef -> seg3 (final edge_path), h -> seg2 (final node_path)
    egat(np2, CN1, 128, EF, CE1, 64, 64, 0, 18, src1, dst1, CE1, seg3, seg2);

    // ---- Stage 3: atom graph ----
    // efeats = repeat(node_path,2): fij GEMM on the 100000 unique rows, edge kernel indexes e>>1.
    // nfeats = nf1 (seg0); GEMMs consume seg0 before fill(h_out=seg0) zeroes it (same-stream order).
    egat(seg0, CN0, 128, seg2, CN1, 128, 128, 1, 25, src0, dst0, CE0, seg1, seg0);
}